// Round 6
// baseline (233.537 us; speedup 1.0000x reference)
//
#include <hip/hip_runtime.h>

#define NB 256
#define NT 1024
#define NL 64

typedef __fp16 h2v __attribute__((ext_vector_type(2)));

__device__ __forceinline__ float rfl_f(float v) {
  return __builtin_bit_cast(float, __builtin_amdgcn_readfirstlane(__builtin_bit_cast(int, v)));
}

// partner = value from lane^1, via DPP quad_perm [1,0,3,2] (VALU, no LDS pipe)
__device__ __forceinline__ float dpp_xor1(float v) {
  int i = __builtin_bit_cast(int, v);
  int r = __builtin_amdgcn_update_dpp(i, i, 0xB1, 0xF, 0xF, false);
  return __builtin_bit_cast(float, r);
}

#define DOT4F(P, B)                                                           \
  s0 = __builtin_amdgcn_fdot2(__builtin_bit_cast(h2v, (P).x), RhF[(B) + 0], s0, false); \
  s1 = __builtin_amdgcn_fdot2(__builtin_bit_cast(h2v, (P).y), RhF[(B) + 1], s1, false); \
  s2 = __builtin_amdgcn_fdot2(__builtin_bit_cast(h2v, (P).z), RhF[(B) + 2], s2, false); \
  s3 = __builtin_amdgcn_fdot2(__builtin_bit_cast(h2v, (P).w), RhF[(B) + 3], s3, false);

#define DOT4B(P, B)                                                           \
  s0 = __builtin_amdgcn_fdot2(__builtin_bit_cast(h2v, (P).x), RhB[(B) + 0], s0, false); \
  s1 = __builtin_amdgcn_fdot2(__builtin_bit_cast(h2v, (P).y), RhB[(B) + 1], s1, false); \
  s2 = __builtin_amdgcn_fdot2(__builtin_bit_cast(h2v, (P).z), RhB[(B) + 2], s2, false); \
  s3 = __builtin_amdgcn_fdot2(__builtin_bit_cast(h2v, (P).w), RhB[(B) + 3], s3, false);

// Fused step-pair: one fwd step + one bwd step of the SAME batch, interleaved
// in one wave. Each half is bit-identical to the round-0 verified CRF_STEP
// (436 cy/step, absmax 0); pairing hides each chain's LDS write->read round
// trip (~250 cy of stall) under the other chain's issue work. Disjoint LDS
// regions (words 0..63 / 64..127); per-wave DS ordering guarantees RAW.
#define STEP2(EFF, EFB)                                                       \
  do {                                                                        \
    float wnF = dpp_xor1(wF);                                                 \
    float wnB = dpp_xor1(wB);                                                 \
    h2v pkF = __builtin_amdgcn_cvt_pkrtz(wF, wnF);                            \
    h2v pkB = __builtin_amdgcn_cvt_pkrtz(wB, wnB);                            \
    lb[wslotF] = __builtin_bit_cast(int, pkF);                                \
    lb[wslotB] = __builtin_bit_cast(int, pkB);                                \
    int4 QF0 = lbvF[0], QF1 = lbvF[1], QF2 = lbvF[2], QF3 = lbvF[3];          \
    int4 QF4 = lbvF[4], QF5 = lbvF[5], QF6 = lbvF[6], QF7 = lbvF[7];          \
    int4 QB0 = lbvB[0], QB1 = lbvB[1], QB2 = lbvB[2], QB3 = lbvB[3];          \
    int4 QB4 = lbvB[4], QB5 = lbvB[5], QB6 = lbvB[6], QB7 = lbvB[7];          \
    int e5F = (QF0.x >> 10) & 0x1f;                                           \
    int e5B = (QB0.x >> 10) & 0x1f;                                           \
    float KEF = __builtin_bit_cast(float, (130 - e5F) << 23) * (EFF);         \
    float KEB = __builtin_bit_cast(float, (130 - e5B) << 23) * (EFB);         \
    e2F += e5F - 3;                                                           \
    e2B += e5B - 3;                                                           \
    {                                                                         \
      float s0 = 0.f, s1 = 0.f, s2 = 0.f, s3 = 0.f;                           \
      DOT4F(QF0, 0); DOT4F(QF1, 4); DOT4F(QF2, 8); DOT4F(QF3, 12);            \
      DOT4F(QF4, 16); DOT4F(QF5, 20); DOT4F(QF6, 24); DOT4F(QF7, 28);         \
      wF = ((s0 + s1) + (s2 + s3)) * KEF;                                     \
    }                                                                         \
    {                                                                         \
      float s0 = 0.f, s1 = 0.f, s2 = 0.f, s3 = 0.f;                           \
      DOT4B(QB0, 0); DOT4B(QB1, 4); DOT4B(QB2, 8); DOT4B(QB3, 12);            \
      DOT4B(QB4, 16); DOT4B(QB5, 20); DOT4B(QB6, 24); DOT4B(QB7, 28);         \
      wB = ((s0 + s1) + (s2 + s3)) * KEB;                                     \
    }                                                                         \
  } while (0)

// F-only step (the 512th fwd step has no bwd partner).
#define STEPF(EFF)                                                            \
  do {                                                                        \
    float wnF = dpp_xor1(wF);                                                 \
    h2v pkF = __builtin_amdgcn_cvt_pkrtz(wF, wnF);                            \
    lb[wslotF] = __builtin_bit_cast(int, pkF);                                \
    int4 QF0 = lbvF[0], QF1 = lbvF[1], QF2 = lbvF[2], QF3 = lbvF[3];          \
    int4 QF4 = lbvF[4], QF5 = lbvF[5], QF6 = lbvF[6], QF7 = lbvF[7];          \
    int e5F = (QF0.x >> 10) & 0x1f;                                           \
    float KEF = __builtin_bit_cast(float, (130 - e5F) << 23) * (EFF);         \
    e2F += e5F - 3;                                                           \
    float s0 = 0.f, s1 = 0.f, s2 = 0.f, s3 = 0.f;                             \
    DOT4F(QF0, 0); DOT4F(QF1, 4); DOT4F(QF2, 8); DOT4F(QF3, 12);              \
    DOT4F(QF4, 16); DOT4F(QF5, 20); DOT4F(QF6, 24); DOT4F(QF7, 28);           \
    wF = ((s0 + s1) + (s2 + s3)) * KEF;                                       \
  } while (0)

#define AQ __ATOMIC_ACQUIRE
#define RL __ATOMIC_RELEASE
#define SCOPE __HIP_MEMORY_SCOPE_AGENT

// 256 blocks x 1 wave: block b runs gold path, then BOTH the fwd and bwd
// chains of batch b interleaved in one wave (2-way ILP on the serial chain),
// then combines alpha+beta+gold in-wave. No flagF/wsA handoff, no contended
// counter (r5's +35us tail = 256 serialized cnt atomics). Block 0 polls the
// 256 per-batch flags (read-only, distinct addresses) and does the r5-verified
// deterministic reduction. 256 waves co-resident trivially (1 block/CU).
__global__ __launch_bounds__(64)
__attribute__((amdgpu_waves_per_eu(1, 1)))
void fb_kernel(const float* __restrict__ scores,
               const int* __restrict__ targets,
               const float* __restrict__ start,
               const float* __restrict__ Tm,
               const float* __restrict__ endv,
               float* __restrict__ wsL,
               int* __restrict__ flagL,
               float* __restrict__ out) {
  const int lane = threadIdx.x;
  const int b = blockIdx.x;
  const float* sc = scores + (size_t)b * NT * NL;
  const float LN2 = 0.69314718055994530942f;

  // ---- gold path (r0 code, ~4us, runs before the chains) ----
  const int* tg = targets + b * NT;
  float gacc = 0.f;
#pragma unroll
  for (int k = 0; k < 16; k++) {
    int t = lane + 64 * k;
    int c = tg[t];
    gacc += sc[t * NL + c];
    if (t > 0) gacc += Tm[c * NL + tg[t - 1]];  // T_mat[cur, prev]
  }
#pragma unroll
  for (int off = 32; off > 0; off >>= 1) gacc += __shfl_xor(gacc, off, 64);
  const float gold = gacc + start[tg[0]] + endv[tg[NT - 1]];

  // ---- LDS: two disjoint 64-word broadcast regions (F: 0..63, B: 64..127) ----
  __shared__ int4 lbv_s[32];
  int* lb = (int*)lbv_s;
  const int4* lbvF = lbv_s;
  const int4* lbvB = lbv_s + 16;
  const int wslot = (lane & 1) * 32 + (lane >> 1);  // 2 lanes/bank -> free
  const int wslotF = wslot;
  const int wslotB = 64 + wslot;

  // ---- f16x2 transition tables (constant indices only -> stay in VGPRs) ----
  // fwd RhF[k] = (exp(T[lane][2k]), exp(T[lane][2k+1]))
  // bwd RhB[k] = (exp(T[2k][lane]), exp(T[2k+1][lane]))
  const float* TbF = Tm + lane * NL;
  const float* TbB = Tm + lane;
  h2v RhF[32], RhB[32];
#pragma unroll
  for (int k = 0; k < 32; k++) {
    RhF[k] = __builtin_amdgcn_cvt_pkrtz(__expf(TbF[2 * k]), __expf(TbF[2 * k + 1]));
    RhB[k] = __builtin_amdgcn_cvt_pkrtz(__expf(TbB[(2 * k) * NL]),
                                        __expf(TbB[(2 * k + 1) * NL]));
  }

  // ---- chain inits (bit-identical to r0) ----
  float a0F = start[lane] + sc[lane];           // alpha_0
  float m0F = rfl_f(a0F);
  float wF = __expf(a0F - m0F) * 16.f;
  int e2F = -4;
  float a0B = endv[lane] + sc[(NT - 1) * NL + lane];  // beta at te=0
  float m0B = rfl_f(a0B);
  float wB = __expf(a0B - m0B) * 16.f;
  int e2B = -4;

  float bF0 = sc[1 * NL + lane], bF1 = sc[2 * NL + lane];
  float bF2 = sc[3 * NL + lane], bF3 = sc[4 * NL + lane];
  float bB0 = sc[1022 * NL + lane], bB1 = sc[1021 * NL + lane];
  float bB2 = sc[1020 * NL + lane], bB3 = sc[1019 * NL + lane];

  // main loop: 127 iters x 4 pairs = F steps t=1..508, B steps te=1022..515
  for (int i = 0; i < 127; i++) {
    int tf = 5 + 4 * i;      // F prefetch rows (max 509..512)
    int tb = 1018 - 4 * i;   // B prefetch rows (min 514..511)
    float nF0 = sc[(tf + 0) * NL + lane], nF1 = sc[(tf + 1) * NL + lane];
    float nF2 = sc[(tf + 2) * NL + lane], nF3 = sc[(tf + 3) * NL + lane];
    float nB0 = sc[(tb - 0) * NL + lane], nB1 = sc[(tb - 1) * NL + lane];
    float nB2 = sc[(tb - 2) * NL + lane], nB3 = sc[(tb - 3) * NL + lane];
    float EF0 = __expf(bF0), EF1 = __expf(bF1), EF2 = __expf(bF2), EF3 = __expf(bF3);
    float EB0 = __expf(bB0), EB1 = __expf(bB1), EB2 = __expf(bB2), EB3 = __expf(bB3);
    STEP2(EF0, EB0);
    STEP2(EF1, EB1);
    STEP2(EF2, EB2);
    STEP2(EF3, EB3);
    bF0 = nF0; bF1 = nF1; bF2 = nF2; bF3 = nF3;
    bB0 = nB0; bB1 = nB1; bB2 = nB2; bB3 = nB3;
  }
  // tail: F t=509..512 (buf rows 509..512); B te=514, 513, then matvec-only
  {
    float EF0 = __expf(bF0), EF1 = __expf(bF1), EF2 = __expf(bF2), EF3 = __expf(bF3);
    float EB0 = __expf(bB0), EB1 = __expf(bB1);  // rows 514, 513
    STEP2(EF0, EB0);
    STEP2(EF1, EB1);
    STEP2(EF2, 1.0f);   // B final matvec-only -> beta_512
    STEPF(EF3);         // F t=512 -> alpha_512
  }

  // ---- in-wave combine: lse over states of alpha+beta, minus gold ----
  float vA = m0F + (float)e2F * LN2 + __logf(wF);
  float vB = m0B + (float)e2B * LN2 + __logf(wB);
  float v = vA + vB;
  float m = v;
#pragma unroll
  for (int off = 32; off > 0; off >>= 1) m = fmaxf(m, __shfl_xor(m, off, 64));
  float s = __expf(v - m);
#pragma unroll
  for (int off = 32; off > 0; off >>= 1) s += __shfl_xor(s, off, 64);
  float loss = (m + __logf(s)) - gold;

  if (lane == 0) {
    wsL[b] = loss;
    __threadfence();
    __hip_atomic_store(&flagL[b], 1, RL, SCOPE);
  }

  // ---- block 0: poll the 256 flags (read-only), deterministic reduction ----
  if (b == 0) {
    for (;;) {
      int f0 = __hip_atomic_load(&flagL[lane], AQ, SCOPE);
      int f1 = __hip_atomic_load(&flagL[lane + 64], AQ, SCOPE);
      int f2 = __hip_atomic_load(&flagL[lane + 128], AQ, SCOPE);
      int f3 = __hip_atomic_load(&flagL[lane + 192], AQ, SCOPE);
      if (__all((f0 & f1 & f2 & f3) != 0)) break;
      __builtin_amdgcn_s_sleep(8);
    }
    float t0 = __builtin_bit_cast(float, __hip_atomic_load((int*)&wsL[lane], AQ, SCOPE));
    float t1 = __builtin_bit_cast(float, __hip_atomic_load((int*)&wsL[lane + 64], AQ, SCOPE));
    float t2 = __builtin_bit_cast(float, __hip_atomic_load((int*)&wsL[lane + 128], AQ, SCOPE));
    float t3 = __builtin_bit_cast(float, __hip_atomic_load((int*)&wsL[lane + 192], AQ, SCOPE));
    float tot = (t0 + t1) + (t2 + t3);
#pragma unroll
    for (int off = 32; off > 0; off >>= 1) tot += __shfl_xor(tot, off, 64);
    if (lane == 0) out[0] = tot * (1.0f / NB);
  }
}

extern "C" void kernel_launch(void* const* d_in, const int* in_sizes, int n_in,
                              void* d_out, int out_size, void* d_ws, size_t ws_size,
                              hipStream_t stream) {
  const float* scores = (const float*)d_in[0];
  const int* targets = (const int*)d_in[1];
  const float* start = (const float*)d_in[2];
  const float* Tm = (const float*)d_in[3];
  const float* endv = (const float*)d_in[4];
  float* out = (float*)d_out;

  int* flagL = (int*)d_ws;             // [NB] per-batch done flags
  float* wsL = (float*)(flagL + NB);   // [NB] per-batch losses

  hipMemsetAsync(flagL, 0, NB * sizeof(int), stream);
  fb_kernel<<<NB, 64, 0, stream>>>(scores, targets, start, Tm, endv, wsL, flagL, out);
}

// Round 7
// 202.643 us; speedup vs baseline: 1.1525x; 1.1525x over previous
//
#include <hip/hip_runtime.h>

#define NB 256
#define NT 1024
#define NL 64

typedef __fp16 h2v __attribute__((ext_vector_type(2)));

__device__ __forceinline__ float rfl_f(float v) {
  return __builtin_bit_cast(float, __builtin_amdgcn_readfirstlane(__builtin_bit_cast(int, v)));
}

// partner = value from lane^1, via DPP quad_perm [1,0,3,2] (VALU, no LDS pipe)
__device__ __forceinline__ float dpp_xor1(float v) {
  int i = __builtin_bit_cast(int, v);
  int r = __builtin_amdgcn_update_dpp(i, i, 0xB1, 0xF, 0xF, false);
  return __builtin_bit_cast(float, r);
}

#define DOT4(P, B)                                                            \
  s0 = __builtin_amdgcn_fdot2(__builtin_bit_cast(h2v, (P).x), Rh[(B) + 0], s0, false); \
  s1 = __builtin_amdgcn_fdot2(__builtin_bit_cast(h2v, (P).y), Rh[(B) + 1], s1, false); \
  s2 = __builtin_amdgcn_fdot2(__builtin_bit_cast(h2v, (P).z), Rh[(B) + 2], s2, false); \
  s3 = __builtin_amdgcn_fdot2(__builtin_bit_cast(h2v, (P).w), Rh[(B) + 3], s3, false);

// One CRF step — BIT-IDENTICAL to the round-0 verified kernel (436 cy/step,
// absmax 0). r1-r4 (gather restructures) and r6 (F/B pairing) both measured
// slower per wall-clock; one chain per wave at 436 cy/step is the floor.
#define CRF_STEP(EF)                                                          \
  do {                                                                        \
    float wn = dpp_xor1(w);                                                   \
    h2v pk = __builtin_amdgcn_cvt_pkrtz(w, wn);                               \
    lb[wslot] = __builtin_bit_cast(int, pk);                                  \
    int4 P0 = lbv[0], P1 = lbv[1], P2 = lbv[2], P3 = lbv[3];                  \
    int4 P4 = lbv[4], P5 = lbv[5], P6 = lbv[6], P7 = lbv[7];                  \
    int e5 = (P0.x >> 10) & 0x1f;                                             \
    float K = __builtin_bit_cast(float, (130 - e5) << 23);                    \
    float KE = K * (EF);                                                      \
    e2 += e5 - 3;                                                             \
    float s0 = 0.f, s1 = 0.f, s2 = 0.f, s3 = 0.f;                             \
    DOT4(P0, 0); DOT4(P1, 4); DOT4(P2, 8); DOT4(P3, 12);                      \
    DOT4(P4, 16); DOT4(P5, 20); DOT4(P6, 24); DOT4(P7, 28);                   \
    w = ((s0 + s1) + (s2 + s3)) * KE;                                         \
  } while (0)

#define AQ __ATOMIC_ACQUIRE
#define RL __ATOMIC_RELEASE
#define SCOPE __HIP_MEMORY_SCOPE_AGENT

// Single fused launch, r0 block layout (the verified-fastest chain config:
// one chain per wave, F and B concurrent on different blocks):
//   blocks 0..255   fwd chain  -> wsA, flagF[b]
//   blocks 256..511 bwd chain  -> beta in regs; spin flagF/flagG; loss ->
//                    wsL, flagL[b]; block 256 (b==0) is the finisher: poll
//                    flagL[0..255] (parallel flag writes, NO serialized
//                    atomic counter — r5's +35us tail), deterministic sum.
//   blocks 512..767 gold path  -> wsG, flagG[b]
// 768 one-wave blocks = 3 waves/CU, all co-resident -> spins are safe.
__global__ __launch_bounds__(64) void fb_kernel(const float* __restrict__ scores,
                                                const int* __restrict__ targets,
                                                const float* __restrict__ start,
                                                const float* __restrict__ Tm,
                                                const float* __restrict__ endv,
                                                float* __restrict__ wsA,
                                                float* __restrict__ wsG,
                                                float* __restrict__ wsL,
                                                int* __restrict__ flagF,
                                                int* __restrict__ flagG,
                                                int* __restrict__ flagL,
                                                float* __restrict__ out) {
  const int lane = threadIdx.x;
  const int bb = blockIdx.x;

  if (bb >= 2 * NB) {  // ---- gold path: one wave per batch ----
    const int b = bb - 2 * NB;
    const int* tg = targets + b * NT;
    const float* sc = scores + (size_t)b * NT * NL;
    float acc = 0.f;
    for (int t = lane; t < NT; t += 64) {
      int c = tg[t];
      acc += sc[t * NL + c];
      if (t > 0) acc += Tm[c * NL + tg[t - 1]];  // T_mat[cur, prev]
    }
#pragma unroll
    for (int off = 32; off > 0; off >>= 1) acc += __shfl_xor(acc, off, 64);
    if (lane == 0) wsG[b] = acc + start[tg[0]] + endv[tg[NT - 1]];
    __threadfence();
    if (lane == 0) __hip_atomic_store(&flagG[b], 1, RL, SCOPE);
    return;
  }

  __shared__ int4 lbv_s[16];        // 64 words: 0..31 = consumed pairs, 32..63 = scratch
  int* lb = (int*)lbv_s;
  const int4* lbv = lbv_s;
  const int wslot = (lane & 1) * 32 + (lane >> 1);  // 2 lanes/bank -> conflict-free

  const bool bwd = bb >= NB;
  const int b = bwd ? bb - NB : bb;
  const float* sc = scores + (size_t)b * NT * NL;
  const float LN2 = 0.69314718055994530942f;

  // f16x2 transition table: fwd Rh[k] = (exp(T[lane][2k]), exp(T[lane][2k+1]))
  //                         bwd Rh[k] = (exp(T[2k][lane]), exp(T[2k+1][lane]))
  const float* Tb = bwd ? (Tm + lane) : (Tm + lane * NL);
  const int str = bwd ? NL : 1;
  h2v Rh[32];
#pragma unroll
  for (int k = 0; k < 32; k++)
    Rh[k] = __builtin_amdgcn_cvt_pkrtz(__expf(Tb[(2 * k) * str]),
                                       __expf(Tb[(2 * k + 1) * str]));

  if (!bwd) {
    float a0 = start[lane] + sc[lane];  // alpha_0
    float m0 = rfl_f(a0);
    float w = __expf(a0 - m0) * 16.f;   // keep w_0 in f16-normal range
    int e2 = -4;

    float buf[4];
#pragma unroll
    for (int k = 0; k < 4; k++) buf[k] = sc[(1 + k) * NL + lane];

    for (int i = 0; i < 128; i++) {  // 512 steps: t = 1..512
      float nb4[4];
      int tb = 5 + 4 * i;  // prefetch (max t=516 < 1024)
#pragma unroll
      for (int k = 0; k < 4; k++) nb4[k] = sc[(tb + k) * NL + lane];
      float Ev[4];
#pragma unroll
      for (int k = 0; k < 4; k++) Ev[k] = __expf(buf[k]);  // off critical chain
      CRF_STEP(Ev[0]);
      CRF_STEP(Ev[1]);
      CRF_STEP(Ev[2]);
      CRF_STEP(Ev[3]);
#pragma unroll
      for (int k = 0; k < 4; k++) buf[k] = nb4[k];
    }
    wsA[b * NL + lane] = m0 + (float)e2 * LN2 + __logf(w);  // alpha_512, coalesced
    __threadfence();
    if (lane == 0) __hip_atomic_store(&flagF[b], 1, RL, SCOPE);
  } else {
    float a0 = endv[lane] + sc[(NT - 1) * NL + lane];
    float m0 = rfl_f(a0);
    float w = __expf(a0 - m0) * 16.f;
    int e2 = -4;

    float buf[4];
#pragma unroll
    for (int k = 0; k < 4; k++) buf[k] = sc[(1022 - k) * NL + lane];

    for (int i = 0; i < 127; i++) {  // 508 steps: te = 1022..515
      float nb4[4];
      int tb = 1018 - 4 * i;  // prefetch (min 511 >= 0)
#pragma unroll
      for (int k = 0; k < 4; k++) nb4[k] = sc[(tb - k) * NL + lane];
      float Ev[4];
#pragma unroll
      for (int k = 0; k < 4; k++) Ev[k] = __expf(buf[k]);
      CRF_STEP(Ev[0]);
      CRF_STEP(Ev[1]);
      CRF_STEP(Ev[2]);
      CRF_STEP(Ev[3]);
#pragma unroll
      for (int k = 0; k < 4; k++) buf[k] = nb4[k];
    }
    CRF_STEP(__expf(sc[514 * NL + lane]));
    CRF_STEP(__expf(sc[513 * NL + lane]));
    CRF_STEP(1.0f);  // final matvec-only step -> beta_512
    float bv = m0 + (float)e2 * LN2 + __logf(w);  // beta_512, stays in reg

    // ---- fused combine: wait for fwd twin, lse(alpha+beta), subtract gold ----
    while (__hip_atomic_load(&flagF[b], AQ, SCOPE) == 0) __builtin_amdgcn_s_sleep(2);
    float v = wsA[b * NL + lane] + bv;
    float m = v;
#pragma unroll
    for (int off = 32; off > 0; off >>= 1) m = fmaxf(m, __shfl_xor(m, off, 64));
    float s = __expf(v - m);
#pragma unroll
    for (int off = 32; off > 0; off >>= 1) s += __shfl_xor(s, off, 64);
    while (__hip_atomic_load(&flagG[b], AQ, SCOPE) == 0) __builtin_amdgcn_s_sleep(2);
    float loss = (m + __logf(s)) - wsG[b];

    if (lane == 0) {
      wsL[b] = loss;
      __threadfence();
      __hip_atomic_store(&flagL[b], 1, RL, SCOPE);
    }

    if (b == 0) {  // ---- finisher: poll flags (parallel writes, no RMW chain) ----
      for (;;) {
        int f0 = __hip_atomic_load(&flagL[lane], AQ, SCOPE);
        int f1 = __hip_atomic_load(&flagL[lane + 64], AQ, SCOPE);
        int f2 = __hip_atomic_load(&flagL[lane + 128], AQ, SCOPE);
        int f3 = __hip_atomic_load(&flagL[lane + 192], AQ, SCOPE);
        if (__all((f0 & f1 & f2 & f3) != 0)) break;
        __builtin_amdgcn_s_sleep(8);
      }
      float t0 = __builtin_bit_cast(float, __hip_atomic_load((int*)&wsL[lane], AQ, SCOPE));
      float t1 = __builtin_bit_cast(float, __hip_atomic_load((int*)&wsL[lane + 64], AQ, SCOPE));
      float t2 = __builtin_bit_cast(float, __hip_atomic_load((int*)&wsL[lane + 128], AQ, SCOPE));
      float t3 = __builtin_bit_cast(float, __hip_atomic_load((int*)&wsL[lane + 192], AQ, SCOPE));
      float tot = (t0 + t1) + (t2 + t3);
#pragma unroll
      for (int off = 32; off > 0; off >>= 1) tot += __shfl_xor(tot, off, 64);
      if (lane == 0) out[0] = tot * (1.0f / NB);
    }
  }
}

extern "C" void kernel_launch(void* const* d_in, const int* in_sizes, int n_in,
                              void* d_out, int out_size, void* d_ws, size_t ws_size,
                              hipStream_t stream) {
  const float* scores = (const float*)d_in[0];
  const int* targets = (const int*)d_in[1];
  const float* start = (const float*)d_in[2];
  const float* Tm = (const float*)d_in[3];
  const float* endv = (const float*)d_in[4];
  float* out = (float*)d_out;

  int* flagF = (int*)d_ws;             // [NB]
  int* flagG = flagF + NB;             // [NB]
  int* flagL = flagG + NB;             // [NB] (+pad to 64-int boundary)
  float* wsG = (float*)(flagL + NB + 64);  // [NB] gold path scores
  float* wsL = wsG + NB;               // [NB] per-batch losses
  float* wsA = wsL + NB;               // [NB*NL] alpha_512, [batch][state]

  hipMemsetAsync(flagF, 0, 3 * NB * sizeof(int), stream);
  fb_kernel<<<3 * NB, 64, 0, stream>>>(scores, targets, start, Tm, endv,
                                       wsA, wsG, wsL, flagF, flagG, flagL, out);
}